// Round 2
// baseline (825.910 us; speedup 1.0000x reference)
//
#include <hip/hip_runtime.h>
#include <math.h>

// N=500000, F=H=128, S=256.
// out = tanh( mlp_l(x) + pooled[seg] ), pooled = lb2+gb2 + segment_mean( mlp_g_pre(x) )
// Structure (ws permitting):
//   prep:   pack W fp16 B-frags; inv_counts; pooled := lb2+gb2  (bias fold)
//   fused:  stage x once, x A-frags in regs; gamma MLP -> reg-reduce -> atomics;
//           lambda MLP -> lam fp16 (LDS repack, coalesced 16B stores) to ws
//   finish: pure stream: out = tanh(lam + pooled[seg]), float4 in/out
// Fallback (small ws): prep + gamma + lambda two-pass (proven round-1 structure).

#define FW 128
#define SEGS 256
#define TILE_R 64
#define XSTR 136   // halfs per LDS row: 272 B; dword stride 68 = 4 mod 32 -> 2-way (free)

typedef __attribute__((ext_vector_type(8))) _Float16 f16x8;
typedef __attribute__((ext_vector_type(4))) _Float16 f16x4;
typedef __attribute__((ext_vector_type(4))) float f32x4;

__device__ __forceinline__ float fast_tanh(float x) {
    float ax = fabsf(x);
    float t = __expf(-2.0f * ax);                // exp2-based, ~1e-6 rel err
    float r = (1.0f - t) / (1.0f + t);
    return __builtin_copysignf(r, x);
}

// --- prep: blocks 0-3 pack W fp32 -> fp16 B-fragments; block 4: inv_counts + pooled=lb2+gb2 ---
// frag f = nt*4 + ks; lane l; P[f*64+l] = 8 fp16: W[ks*32 + (l>>4)*8 + j][nt*16 + (l&15)]
__global__ void prep_kernel(const float* __restrict__ W0, const float* __restrict__ W1,
                            const float* __restrict__ W2, const float* __restrict__ W3,
                            uint4* __restrict__ P0, uint4* __restrict__ P1,
                            uint4* __restrict__ P2, uint4* __restrict__ P3,
                            const int* __restrict__ seg, float* __restrict__ inv_counts,
                            float* __restrict__ pooled,
                            const float* __restrict__ lb2, const float* __restrict__ gb2, int N)
{
    if (blockIdx.x == 4) {
        int s = threadIdx.x;
        // pooled[s][c] = lb2[c] + gb2[c]  (bias fold; overwritten-by-add later via atomics)
        for (int i = s; i < SEGS * FW; i += 256) {
            int c = i & (FW - 1);
            pooled[i] = lb2[c] + gb2[c];
        }
        // per-segment count via binary search over sorted segment_ids
        int lo0 = 0, hi0 = N;
        while (lo0 < hi0) { int mid = (lo0 + hi0) >> 1; if (seg[mid] < s) lo0 = mid + 1; else hi0 = mid; }
        int lo1 = lo0, hi1 = N;
        while (lo1 < hi1) { int mid = (lo1 + hi1) >> 1; if (seg[mid] < s + 1) lo1 = mid + 1; else hi1 = mid; }
        int c = lo1 - lo0;
        inv_counts[s] = 1.0f / (float)(c > 0 ? c : 1);
        return;
    }
    const float* W = blockIdx.x == 0 ? W0 : blockIdx.x == 1 ? W1 : blockIdx.x == 2 ? W2 : W3;
    uint4*       P = blockIdx.x == 0 ? P0 : blockIdx.x == 1 ? P1 : blockIdx.x == 2 ? P2 : P3;
    for (int s = threadIdx.x; s < 32 * 64; s += 256) {
        int f = s >> 6, l = s & 63;
        int nt = f >> 2, ks = f & 3;
        int n = nt * 16 + (l & 15);
        int k0 = ks * 32 + ((l >> 4) << 3);
        union { _Float16 h[8]; uint4 q; } u;
        #pragma unroll
        for (int j = 0; j < 8; ++j) u.h[j] = (_Float16)W[(k0 + j) * FW + n];
        P[s] = u.q;
    }
}

// --- stage x tile: fp32 -> fp16 in LDS (coalesced float4 reads, 8B LDS writes) ---
__device__ __forceinline__ void stage_x(_Float16* A, const float* __restrict__ x, int r0, int N) {
    const float4* x4 = (const float4*)x;
    bool full = (r0 + TILE_R <= N);
    for (int j = threadIdx.x; j < TILE_R * 32; j += 256) {
        int row = j >> 5, c4 = j & 31;
        float4 v = make_float4(0.f, 0.f, 0.f, 0.f);
        if (full || r0 + row < N) v = x4[(long)r0 * 32 + j];
        f16x4 h;
        h.x = (_Float16)v.x; h.y = (_Float16)v.y; h.z = (_Float16)v.z; h.w = (_Float16)v.w;
        *(f16x4*)&A[row * XSTR + c4 * 4] = h;
    }
}

// --- one MFMA layer from register A-frags ---
__device__ __forceinline__ void mfma_layer_r(const f16x8 af[4], const uint4* __restrict__ Wp,
                                             int lane, f32x4 acc[8])
{
    #pragma unroll
    for (int nt = 0; nt < 8; ++nt) acc[nt] = (f32x4){0.f, 0.f, 0.f, 0.f};
    #pragma unroll
    for (int ks = 0; ks < 4; ++ks) {
        #pragma unroll
        for (int nt = 0; nt < 8; ++nt) {
            f16x8 b = __builtin_bit_cast(f16x8, Wp[(nt * 4 + ks) * 64 + lane]);
            acc[nt] = __builtin_amdgcn_mfma_f32_16x16x32_f16(af[ks], b, acc[nt], 0, 0, 0);
        }
    }
}

// --- h = relu(acc + b1) -> fp16 in place; rows are wave-private after the stage barrier ---
__device__ __forceinline__ void write_h(_Float16* A, const f32x4 acc[8],
                                        const float* __restrict__ b1, int wv, int l15, int q)
{
    #pragma unroll
    for (int nt = 0; nt < 8; ++nt) {
        float bias = b1[nt * 16 + l15];
        #pragma unroll
        for (int r = 0; r < 4; ++r)
            A[(wv * 16 + q * 4 + r) * XSTR + nt * 16 + l15] =
                (_Float16)fmaxf(acc[nt][r] + bias, 0.f);
    }
}

// --- load h A-frags; fence pins intra-wave RAW on the in-place overwrite (rule-18 pattern) ---
__device__ __forceinline__ void load_hf(const _Float16* A, int abase, f16x8 hf[4]) {
    asm volatile("s_waitcnt lgkmcnt(0)" ::: "memory");
    __builtin_amdgcn_sched_barrier(0);
    #pragma unroll
    for (int ks = 0; ks < 4; ++ks) hf[ks] = *(const f16x8*)&A[abase + ks * 32];
}

// --- in-register segmented mean-reduction + atomics ---
__device__ __forceinline__ void reduce_pool(const f32x4 acc[8], const int* segs,
    const float* __restrict__ inv_counts, float* __restrict__ pooled,
    int wv, int l15, int q)
{
    int rb = wv * 16;
    int sF = segs[rb], sL = segs[rb + 15];
    if (sF == sL) {                               // common case: one segment (or all OOB)
        if (sF >= 0) {
            float ic = inv_counts[sF];
            #pragma unroll
            for (int nt = 0; nt < 8; ++nt) {
                float t = (acc[nt][0] + acc[nt][1]) + (acc[nt][2] + acc[nt][3]);
                t += __shfl_xor(t, 16);
                t += __shfl_xor(t, 32);
                if (q == 0) atomicAdd(&pooled[sF * FW + nt * 16 + l15], t * ic);
            }
        }
    } else {                                      // boundary tile: walk runs (wave-uniform)
        int i = 0;
        while (i < 16) {
            int s = segs[rb + i];
            int e = i + 1;
            while (e < 16 && segs[rb + e] == s) ++e;
            if (s >= 0) {
                float ic = inv_counts[s];
                #pragma unroll
                for (int nt = 0; nt < 8; ++nt) {
                    float t = 0.f;
                    #pragma unroll
                    for (int r = 0; r < 4; ++r) {
                        int lr = q * 4 + r;
                        t += (lr >= i && lr < e) ? acc[nt][r] : 0.f;
                    }
                    t += __shfl_xor(t, 16);
                    t += __shfl_xor(t, 32);
                    if (q == 0) atomicAdd(&pooled[s * FW + nt * 16 + l15], t * ic);
                }
            }
            i = e;
        }
    }
}

// === fused pass: gamma (atomics) + lambda (lam fp16 to ws) with ONE x read ===
__global__ __launch_bounds__(256, 8) void fused_kernel(
    const float* __restrict__ x, const int* __restrict__ seg,
    const uint4* __restrict__ Wg1, const float* __restrict__ gb1, const uint4* __restrict__ Wg2,
    const uint4* __restrict__ Wl1, const float* __restrict__ lb1, const uint4* __restrict__ Wl2,
    const float* __restrict__ inv_counts, float* __restrict__ pooled,
    unsigned short* __restrict__ lam, int N)
{
    __shared__ _Float16 A[TILE_R * XSTR];
    __shared__ int segs[TILE_R];
    int tid = threadIdx.x;
    int r0 = blockIdx.x * TILE_R;
    stage_x(A, x, r0, N);
    if (tid < TILE_R) segs[tid] = (r0 + tid < N) ? seg[r0 + tid] : -1;
    __syncthreads();

    int wv = tid >> 6, lane = tid & 63;
    int l15 = lane & 15, q = lane >> 4;
    int abase = (wv * 16 + l15) * XSTR + q * 8;

    // x A-frags -> registers (16 VGPR); frees LDS x region for in-place h
    f16x8 xf[4];
    #pragma unroll
    for (int ks = 0; ks < 4; ++ks) xf[ks] = *(const f16x8*)&A[abase + ks * 32];

    f32x4 acc[8];
    f16x8 hf[4];

    // ---- gamma branch ----
    mfma_layer_r(xf, Wg1, lane, acc);
    write_h(A, acc, gb1, wv, l15, q);
    load_hf(A, abase, hf);
    mfma_layer_r(hf, Wg2, lane, acc);
    reduce_pool(acc, segs, inv_counts, pooled, wv, l15, q);

    // ---- lambda branch (x frags still live in regs) ----
    mfma_layer_r(xf, Wl1, lane, acc);
    write_h(A, acc, lb1, wv, l15, q);
    load_hf(A, abase, hf);
    mfma_layer_r(hf, Wl2, lane, acc);

    // lam (pre-bias2) -> fp16 into A (x dead), rows wave-private; then coalesced store
    #pragma unroll
    for (int nt = 0; nt < 8; ++nt) {
        #pragma unroll
        for (int r = 0; r < 4; ++r)
            A[(wv * 16 + q * 4 + r) * XSTR + nt * 16 + l15] = (_Float16)acc[nt][r];
    }
    __syncthreads();

    int orow = tid >> 2, ch = tid & 3;            // 64 rows x 4 chunks of 32 halfs
    int grow = r0 + orow;
    if (grow < N) {
        const uint4* src = (const uint4*)&A[orow * XSTR + ch * 32];
        uint4* dst = (uint4*)(lam + (long)grow * FW + ch * 32);
        uint4 v0 = src[0], v1 = src[1], v2 = src[2], v3 = src[3];
        dst[0] = v0; dst[1] = v1; dst[2] = v2; dst[3] = v3;
    }
}

// === finish pass: pure stream, out = tanh(lam + pooled[seg]) ===
__global__ __launch_bounds__(256, 8) void finish_kernel(
    const unsigned short* __restrict__ lam, const int* __restrict__ seg,
    const float* __restrict__ pooled, float* __restrict__ out, int N)
{
    long stride = (long)gridDim.x * blockDim.x;
    long ngroups = (long)N * (FW / 8);
    for (long g = (long)blockIdx.x * blockDim.x + threadIdx.x; g < ngroups; g += stride) {
        int row = (int)(g >> 4);
        int c0 = ((int)g & 15) * 8;
        int s = seg[row];
        f16x8 lv = *(const f16x8*)(lam + g * 8);
        const float4* pr = (const float4*)(pooled + s * FW + c0);
        float4 p0 = pr[0], p1 = pr[1];
        float4 o0, o1;
        o0.x = fast_tanh((float)lv[0] + p0.x);
        o0.y = fast_tanh((float)lv[1] + p0.y);
        o0.z = fast_tanh((float)lv[2] + p0.z);
        o0.w = fast_tanh((float)lv[3] + p0.w);
        o1.x = fast_tanh((float)lv[4] + p1.x);
        o1.y = fast_tanh((float)lv[5] + p1.y);
        o1.z = fast_tanh((float)lv[6] + p1.z);
        o1.w = fast_tanh((float)lv[7] + p1.w);
        float4* dst = (float4*)(out + g * 8);
        dst[0] = o0; dst[1] = o1;
    }
}

// === fallback two-pass (used only if ws too small for lam) ===
__global__ __launch_bounds__(256, 8) void gamma_fb(
    const float* __restrict__ x, const int* __restrict__ seg,
    const uint4* __restrict__ Wp1, const float* __restrict__ b1,
    const uint4* __restrict__ Wp2,
    const float* __restrict__ inv_counts, float* __restrict__ pooled, int N)
{
    __shared__ _Float16 A[TILE_R * XSTR];
    __shared__ int segs[TILE_R];
    int tid = threadIdx.x;
    int r0 = blockIdx.x * TILE_R;
    stage_x(A, x, r0, N);
    if (tid < TILE_R) segs[tid] = (r0 + tid < N) ? seg[r0 + tid] : -1;
    __syncthreads();

    int wv = tid >> 6, lane = tid & 63;
    int l15 = lane & 15, q = lane >> 4;
    int abase = (wv * 16 + l15) * XSTR + q * 8;
    f16x8 xf[4];
    #pragma unroll
    for (int ks = 0; ks < 4; ++ks) xf[ks] = *(const f16x8*)&A[abase + ks * 32];
    f32x4 acc[8];
    f16x8 hf[4];
    mfma_layer_r(xf, Wp1, lane, acc);
    write_h(A, acc, b1, wv, l15, q);
    load_hf(A, abase, hf);
    mfma_layer_r(hf, Wp2, lane, acc);
    reduce_pool(acc, segs, inv_counts, pooled, wv, l15, q);
}

__global__ __launch_bounds__(256, 8) void lambda_fb(
    const float* __restrict__ x, const int* __restrict__ seg,
    const uint4* __restrict__ Wp1, const float* __restrict__ b1,
    const uint4* __restrict__ Wp2,
    const float* __restrict__ pooled, float* __restrict__ out, int N)
{
    __shared__ _Float16 A[TILE_R * XSTR];
    __shared__ int segs[TILE_R];
    int tid = threadIdx.x;
    int r0 = blockIdx.x * TILE_R;
    stage_x(A, x, r0, N);
    if (tid < TILE_R) segs[tid] = (r0 + tid < N) ? seg[r0 + tid] : -1;
    __syncthreads();

    int wv = tid >> 6, lane = tid & 63;
    int l15 = lane & 15, q = lane >> 4;
    int abase = (wv * 16 + l15) * XSTR + q * 8;
    f16x8 xf[4];
    #pragma unroll
    for (int ks = 0; ks < 4; ++ks) xf[ks] = *(const f16x8*)&A[abase + ks * 32];
    f32x4 acc[8];
    f16x8 hf[4];
    mfma_layer_r(xf, Wp1, lane, acc);
    write_h(A, acc, b1, wv, l15, q);
    load_hf(A, abase, hf);
    mfma_layer_r(hf, Wp2, lane, acc);

    #pragma unroll
    for (int r = 0; r < 4; ++r) {
        int lrow = wv * 16 + q * 4 + r;
        int row = r0 + lrow;
        if (row < N) {
            const float* prow = &pooled[segs[lrow] * FW];
            #pragma unroll
            for (int nt = 0; nt < 8; ++nt) {
                int col = nt * 16 + l15;
                out[(long)row * FW + col] = fast_tanh(acc[nt][r] + prow[col]);
            }
        }
    }
}

extern "C" void kernel_launch(void* const* d_in, const int* in_sizes, int n_in,
                              void* d_out, int out_size, void* d_ws, size_t ws_size,
                              hipStream_t stream) {
    const float* x   = (const float*)d_in[0];
    const int*   seg = (const int*)  d_in[1];
    const float* lW1 = (const float*)d_in[2];
    const float* lb1 = (const float*)d_in[3];
    const float* lW2 = (const float*)d_in[4];
    const float* lb2 = (const float*)d_in[5];
    const float* gW1 = (const float*)d_in[6];
    const float* gb1 = (const float*)d_in[7];
    const float* gW2 = (const float*)d_in[8];
    const float* gb2 = (const float*)d_in[9];
    float* out = (float*)d_out;

    const int N = in_sizes[0] / FW;            // 500000

    char* ws = (char*)d_ws;
    float* pooled     = (float*)ws;                         // 256*128*4 = 131072 B
    float* inv_counts = (float*)(ws + 131072);              // 1024 B
    uint4* WpL1 = (uint4*)(ws + 132096);                    // 32 KB each
    uint4* WpL2 = WpL1 + 2048;
    uint4* WpG1 = WpL2 + 2048;
    uint4* WpG2 = WpG1 + 2048;
    const size_t lam_off = 263168;                          // 16B-aligned
    unsigned short* lam = (unsigned short*)(ws + lam_off);
    size_t need = lam_off + (size_t)N * FW * sizeof(unsigned short);  // ~128.25 MB

    prep_kernel<<<5, 256, 0, stream>>>(lW1, lW2, gW1, gW2, WpL1, WpL2, WpG1, WpG2,
                                       seg, inv_counts, pooled, lb2, gb2, N);

    int nb = (N + TILE_R - 1) / TILE_R;        // 7813
    if (ws_size >= need) {
        fused_kernel<<<nb, 256, 0, stream>>>(x, seg, WpG1, gb1, WpG2, WpL1, lb1, WpL2,
                                             inv_counts, pooled, lam, N);
        finish_kernel<<<2048, 256, 0, stream>>>(lam, seg, pooled, out, N);
    } else {
        gamma_fb<<<nb, 256, 0, stream>>>(x, seg, WpG1, gb1, WpG2, inv_counts, pooled, N);
        lambda_fb<<<nb, 256, 0, stream>>>(x, seg, WpL1, lb1, WpL2, pooled, out, N);
    }
}

// Round 3
// 678.353 us; speedup vs baseline: 1.2175x; 1.2175x over previous
//
#include <hip/hip_runtime.h>
#include <math.h>

// N=500000, F=H=128, S=256.
// out = tanh( mlp_l(x) + pooled[seg] ), pooled = lb2+gb2 + segment_mean( mlp_g_pre(x) )
// Structure (ws permitting):
//   prep:   pack W fp16 B-frags; inv_counts; pooled := lb2+gb2  (bias fold)
//   fused:  stage x once, x A-frags in regs; gamma MLP -> reg-reduce -> atomics;
//           lambda MLP -> lam fp16 (LDS repack, coalesced 16B stores) to ws
//   finish: pure stream: out = tanh(lam + pooled[seg]), float4 in/out
// Round-3 fix: __launch_bounds__(256,4) on MFMA kernels. (256,8) capped the
// unified VGPR+AGPR budget at 64/wave -> xf/hf/acc spilled to scratch
// (round-2 counters: +519 MB writes, +117 MB reads, VALUBusy 7.9%).

#define FW 128
#define SEGS 256
#define TILE_R 64
#define XSTR 136   // halfs per LDS row: 272 B; dword stride 68 = 4 mod 32 -> 2-way (free)

typedef __attribute__((ext_vector_type(8))) _Float16 f16x8;
typedef __attribute__((ext_vector_type(4))) _Float16 f16x4;
typedef __attribute__((ext_vector_type(4))) float f32x4;

__device__ __forceinline__ float fast_tanh(float x) {
    float ax = fabsf(x);
    float t = __expf(-2.0f * ax);                // exp2-based, ~1e-6 rel err
    float r = (1.0f - t) / (1.0f + t);
    return __builtin_copysignf(r, x);
}

// --- prep: blocks 0-3 pack W fp32 -> fp16 B-fragments; block 4: inv_counts + pooled=lb2+gb2 ---
// frag f = nt*4 + ks; lane l; P[f*64+l] = 8 fp16: W[ks*32 + (l>>4)*8 + j][nt*16 + (l&15)]
__global__ void prep_kernel(const float* __restrict__ W0, const float* __restrict__ W1,
                            const float* __restrict__ W2, const float* __restrict__ W3,
                            uint4* __restrict__ P0, uint4* __restrict__ P1,
                            uint4* __restrict__ P2, uint4* __restrict__ P3,
                            const int* __restrict__ seg, float* __restrict__ inv_counts,
                            float* __restrict__ pooled,
                            const float* __restrict__ lb2, const float* __restrict__ gb2, int N)
{
    if (blockIdx.x == 4) {
        int s = threadIdx.x;
        // pooled[s][c] = lb2[c] + gb2[c]  (bias fold; atomics add the mean on top)
        for (int i = s; i < SEGS * FW; i += 256) {
            int c = i & (FW - 1);
            pooled[i] = lb2[c] + gb2[c];
        }
        // per-segment count via binary search over sorted segment_ids
        int lo0 = 0, hi0 = N;
        while (lo0 < hi0) { int mid = (lo0 + hi0) >> 1; if (seg[mid] < s) lo0 = mid + 1; else hi0 = mid; }
        int lo1 = lo0, hi1 = N;
        while (lo1 < hi1) { int mid = (lo1 + hi1) >> 1; if (seg[mid] < s + 1) lo1 = mid + 1; else hi1 = mid; }
        int c = lo1 - lo0;
        inv_counts[s] = 1.0f / (float)(c > 0 ? c : 1);
        return;
    }
    const float* W = blockIdx.x == 0 ? W0 : blockIdx.x == 1 ? W1 : blockIdx.x == 2 ? W2 : W3;
    uint4*       P = blockIdx.x == 0 ? P0 : blockIdx.x == 1 ? P1 : blockIdx.x == 2 ? P2 : P3;
    for (int s = threadIdx.x; s < 32 * 64; s += 256) {
        int f = s >> 6, l = s & 63;
        int nt = f >> 2, ks = f & 3;
        int n = nt * 16 + (l & 15);
        int k0 = ks * 32 + ((l >> 4) << 3);
        union { _Float16 h[8]; uint4 q; } u;
        #pragma unroll
        for (int j = 0; j < 8; ++j) u.h[j] = (_Float16)W[(k0 + j) * FW + n];
        P[s] = u.q;
    }
}

// --- stage x tile: fp32 -> fp16 in LDS (coalesced float4 reads, 8B LDS writes) ---
__device__ __forceinline__ void stage_x(_Float16* A, const float* __restrict__ x, int r0, int N) {
    const float4* x4 = (const float4*)x;
    bool full = (r0 + TILE_R <= N);
    for (int j = threadIdx.x; j < TILE_R * 32; j += 256) {
        int row = j >> 5, c4 = j & 31;
        float4 v = make_float4(0.f, 0.f, 0.f, 0.f);
        if (full || r0 + row < N) v = x4[(long)r0 * 32 + j];
        f16x4 h;
        h.x = (_Float16)v.x; h.y = (_Float16)v.y; h.z = (_Float16)v.z; h.w = (_Float16)v.w;
        *(f16x4*)&A[row * XSTR + c4 * 4] = h;
    }
}

// --- one MFMA layer from register A-frags ---
__device__ __forceinline__ void mfma_layer_r(const f16x8 af[4], const uint4* __restrict__ Wp,
                                             int lane, f32x4 acc[8])
{
    #pragma unroll
    for (int nt = 0; nt < 8; ++nt) acc[nt] = (f32x4){0.f, 0.f, 0.f, 0.f};
    #pragma unroll
    for (int ks = 0; ks < 4; ++ks) {
        #pragma unroll
        for (int nt = 0; nt < 8; ++nt) {
            f16x8 b = __builtin_bit_cast(f16x8, Wp[(nt * 4 + ks) * 64 + lane]);
            acc[nt] = __builtin_amdgcn_mfma_f32_16x16x32_f16(af[ks], b, acc[nt], 0, 0, 0);
        }
    }
}

// --- h = relu(acc + b1) -> fp16 in place; rows are wave-private after the stage barrier ---
__device__ __forceinline__ void write_h(_Float16* A, const f32x4 acc[8],
                                        const float* __restrict__ b1, int wv, int l15, int q)
{
    #pragma unroll
    for (int nt = 0; nt < 8; ++nt) {
        float bias = b1[nt * 16 + l15];
        #pragma unroll
        for (int r = 0; r < 4; ++r)
            A[(wv * 16 + q * 4 + r) * XSTR + nt * 16 + l15] =
                (_Float16)fmaxf(acc[nt][r] + bias, 0.f);
    }
}

// --- load h A-frags; fence pins intra-wave RAW on the in-place overwrite (rule-18 pattern) ---
__device__ __forceinline__ void load_hf(const _Float16* A, int abase, f16x8 hf[4]) {
    asm volatile("s_waitcnt lgkmcnt(0)" ::: "memory");
    __builtin_amdgcn_sched_barrier(0);
    #pragma unroll
    for (int ks = 0; ks < 4; ++ks) hf[ks] = *(const f16x8*)&A[abase + ks * 32];
}

// --- in-register segmented mean-reduction + atomics ---
__device__ __forceinline__ void reduce_pool(const f32x4 acc[8], const int* segs,
    const float* __restrict__ inv_counts, float* __restrict__ pooled,
    int wv, int l15, int q)
{
    int rb = wv * 16;
    int sF = segs[rb], sL = segs[rb + 15];
    if (sF == sL) {                               // common case: one segment (or all OOB)
        if (sF >= 0) {
            float ic = inv_counts[sF];
            #pragma unroll
            for (int nt = 0; nt < 8; ++nt) {
                float t = (acc[nt][0] + acc[nt][1]) + (acc[nt][2] + acc[nt][3]);
                t += __shfl_xor(t, 16);
                t += __shfl_xor(t, 32);
                if (q == 0) atomicAdd(&pooled[sF * FW + nt * 16 + l15], t * ic);
            }
        }
    } else {                                      // boundary tile: walk runs (wave-uniform)
        int i = 0;
        while (i < 16) {
            int s = segs[rb + i];
            int e = i + 1;
            while (e < 16 && segs[rb + e] == s) ++e;
            if (s >= 0) {
                float ic = inv_counts[s];
                #pragma unroll
                for (int nt = 0; nt < 8; ++nt) {
                    float t = 0.f;
                    #pragma unroll
                    for (int r = 0; r < 4; ++r) {
                        int lr = q * 4 + r;
                        t += (lr >= i && lr < e) ? acc[nt][r] : 0.f;
                    }
                    t += __shfl_xor(t, 16);
                    t += __shfl_xor(t, 32);
                    if (q == 0) atomicAdd(&pooled[s * FW + nt * 16 + l15], t * ic);
                }
            }
            i = e;
        }
    }
}

// === fused pass: gamma (atomics) + lambda (lam fp16 to ws) with ONE x read ===
__global__ __launch_bounds__(256, 4) void fused_kernel(
    const float* __restrict__ x, const int* __restrict__ seg,
    const uint4* __restrict__ Wg1, const float* __restrict__ gb1, const uint4* __restrict__ Wg2,
    const uint4* __restrict__ Wl1, const float* __restrict__ lb1, const uint4* __restrict__ Wl2,
    const float* __restrict__ inv_counts, float* __restrict__ pooled,
    unsigned short* __restrict__ lam, int N)
{
    __shared__ _Float16 A[TILE_R * XSTR];
    __shared__ int segs[TILE_R];
    int tid = threadIdx.x;
    int r0 = blockIdx.x * TILE_R;
    stage_x(A, x, r0, N);
    if (tid < TILE_R) segs[tid] = (r0 + tid < N) ? seg[r0 + tid] : -1;
    __syncthreads();

    int wv = tid >> 6, lane = tid & 63;
    int l15 = lane & 15, q = lane >> 4;
    int abase = (wv * 16 + l15) * XSTR + q * 8;

    // x A-frags -> registers (16 VGPR); frees LDS x region for in-place h
    f16x8 xf[4];
    #pragma unroll
    for (int ks = 0; ks < 4; ++ks) xf[ks] = *(const f16x8*)&A[abase + ks * 32];

    f32x4 acc[8];
    f16x8 hf[4];

    // ---- gamma branch ----
    mfma_layer_r(xf, Wg1, lane, acc);
    write_h(A, acc, gb1, wv, l15, q);
    load_hf(A, abase, hf);
    mfma_layer_r(hf, Wg2, lane, acc);
    reduce_pool(acc, segs, inv_counts, pooled, wv, l15, q);

    // ---- lambda branch (x frags still live in regs) ----
    mfma_layer_r(xf, Wl1, lane, acc);
    write_h(A, acc, lb1, wv, l15, q);
    load_hf(A, abase, hf);
    mfma_layer_r(hf, Wl2, lane, acc);

    // lam (pre-bias2) -> fp16 into A (x dead), rows wave-private; then coalesced store
    #pragma unroll
    for (int nt = 0; nt < 8; ++nt) {
        #pragma unroll
        for (int r = 0; r < 4; ++r)
            A[(wv * 16 + q * 4 + r) * XSTR + nt * 16 + l15] = (_Float16)acc[nt][r];
    }
    __syncthreads();

    int orow = tid >> 2, ch = tid & 3;            // 64 rows x 4 chunks of 32 halfs
    int grow = r0 + orow;
    if (grow < N) {
        const uint4* src = (const uint4*)&A[orow * XSTR + ch * 32];
        uint4* dst = (uint4*)(lam + (long)grow * FW + ch * 32);
        uint4 v0 = src[0], v1 = src[1], v2 = src[2], v3 = src[3];
        dst[0] = v0; dst[1] = v1; dst[2] = v2; dst[3] = v3;
    }
}

// === finish pass: pure stream, out = tanh(lam + pooled[seg]) ===
__global__ __launch_bounds__(256, 8) void finish_kernel(
    const unsigned short* __restrict__ lam, const int* __restrict__ seg,
    const float* __restrict__ pooled, float* __restrict__ out, int N)
{
    long stride = (long)gridDim.x * blockDim.x;
    long ngroups = (long)N * (FW / 8);
    for (long g = (long)blockIdx.x * blockDim.x + threadIdx.x; g < ngroups; g += stride) {
        int row = (int)(g >> 4);
        int c0 = ((int)g & 15) * 8;
        int s = seg[row];
        f16x8 lv = *(const f16x8*)(lam + g * 8);
        const float4* pr = (const float4*)(pooled + s * FW + c0);
        float4 p0 = pr[0], p1 = pr[1];
        float4 o0, o1;
        o0.x = fast_tanh((float)lv[0] + p0.x);
        o0.y = fast_tanh((float)lv[1] + p0.y);
        o0.z = fast_tanh((float)lv[2] + p0.z);
        o0.w = fast_tanh((float)lv[3] + p0.w);
        o1.x = fast_tanh((float)lv[4] + p1.x);
        o1.y = fast_tanh((float)lv[5] + p1.y);
        o1.z = fast_tanh((float)lv[6] + p1.z);
        o1.w = fast_tanh((float)lv[7] + p1.w);
        float4* dst = (float4*)(out + g * 8);
        dst[0] = o0; dst[1] = o1;
    }
}

// === fallback two-pass (used only if ws too small for lam) ===
__global__ __launch_bounds__(256, 4) void gamma_fb(
    const float* __restrict__ x, const int* __restrict__ seg,
    const uint4* __restrict__ Wp1, const float* __restrict__ b1,
    const uint4* __restrict__ Wp2,
    const float* __restrict__ inv_counts, float* __restrict__ pooled, int N)
{
    __shared__ _Float16 A[TILE_R * XSTR];
    __shared__ int segs[TILE_R];
    int tid = threadIdx.x;
    int r0 = blockIdx.x * TILE_R;
    stage_x(A, x, r0, N);
    if (tid < TILE_R) segs[tid] = (r0 + tid < N) ? seg[r0 + tid] : -1;
    __syncthreads();

    int wv = tid >> 6, lane = tid & 63;
    int l15 = lane & 15, q = lane >> 4;
    int abase = (wv * 16 + l15) * XSTR + q * 8;
    f16x8 xf[4];
    #pragma unroll
    for (int ks = 0; ks < 4; ++ks) xf[ks] = *(const f16x8*)&A[abase + ks * 32];
    f32x4 acc[8];
    f16x8 hf[4];
    mfma_layer_r(xf, Wp1, lane, acc);
    write_h(A, acc, b1, wv, l15, q);
    load_hf(A, abase, hf);
    mfma_layer_r(hf, Wp2, lane, acc);
    reduce_pool(acc, segs, inv_counts, pooled, wv, l15, q);
}

__global__ __launch_bounds__(256, 4) void lambda_fb(
    const float* __restrict__ x, const int* __restrict__ seg,
    const uint4* __restrict__ Wp1, const float* __restrict__ b1,
    const uint4* __restrict__ Wp2,
    const float* __restrict__ pooled, float* __restrict__ out, int N)
{
    __shared__ _Float16 A[TILE_R * XSTR];
    __shared__ int segs[TILE_R];
    int tid = threadIdx.x;
    int r0 = blockIdx.x * TILE_R;
    stage_x(A, x, r0, N);
    if (tid < TILE_R) segs[tid] = (r0 + tid < N) ? seg[r0 + tid] : -1;
    __syncthreads();

    int wv = tid >> 6, lane = tid & 63;
    int l15 = lane & 15, q = lane >> 4;
    int abase = (wv * 16 + l15) * XSTR + q * 8;
    f16x8 xf[4];
    #pragma unroll
    for (int ks = 0; ks < 4; ++ks) xf[ks] = *(const f16x8*)&A[abase + ks * 32];
    f32x4 acc[8];
    f16x8 hf[4];
    mfma_layer_r(xf, Wp1, lane, acc);
    write_h(A, acc, b1, wv, l15, q);
    load_hf(A, abase, hf);
    mfma_layer_r(hf, Wp2, lane, acc);

    #pragma unroll
    for (int r = 0; r < 4; ++r) {
        int lrow = wv * 16 + q * 4 + r;
        int row = r0 + lrow;
        if (row < N) {
            const float* prow = &pooled[segs[lrow] * FW];
            #pragma unroll
            for (int nt = 0; nt < 8; ++nt) {
                int col = nt * 16 + l15;
                out[(long)row * FW + col] = fast_tanh(acc[nt][r] + prow[col]);
            }
        }
    }
}

extern "C" void kernel_launch(void* const* d_in, const int* in_sizes, int n_in,
                              void* d_out, int out_size, void* d_ws, size_t ws_size,
                              hipStream_t stream) {
    const float* x   = (const float*)d_in[0];
    const int*   seg = (const int*)  d_in[1];
    const float* lW1 = (const float*)d_in[2];
    const float* lb1 = (const float*)d_in[3];
    const float* lW2 = (const float*)d_in[4];
    const float* lb2 = (const float*)d_in[5];
    const float* gW1 = (const float*)d_in[6];
    const float* gb1 = (const float*)d_in[7];
    const float* gW2 = (const float*)d_in[8];
    const float* gb2 = (const float*)d_in[9];
    float* out = (float*)d_out;

    const int N = in_sizes[0] / FW;            // 500000

    char* ws = (char*)d_ws;
    float* pooled     = (float*)ws;                         // 256*128*4 = 131072 B
    float* inv_counts = (float*)(ws + 131072);              // 1024 B
    uint4* WpL1 = (uint4*)(ws + 132096);                    // 32 KB each
    uint4* WpL2 = WpL1 + 2048;
    uint4* WpG1 = WpL2 + 2048;
    uint4* WpG2 = WpG1 + 2048;
    const size_t lam_off = 263168;                          // 16B-aligned
    unsigned short* lam = (unsigned short*)(ws + lam_off);
    size_t need = lam_off + (size_t)N * FW * sizeof(unsigned short);  // ~128.25 MB

    prep_kernel<<<5, 256, 0, stream>>>(lW1, lW2, gW1, gW2, WpL1, WpL2, WpG1, WpG2,
                                       seg, inv_counts, pooled, lb2, gb2, N);

    int nb = (N + TILE_R - 1) / TILE_R;        // 7813
    if (ws_size >= need) {
        fused_kernel<<<nb, 256, 0, stream>>>(x, seg, WpG1, gb1, WpG2, WpL1, lb1, WpL2,
                                             inv_counts, pooled, lam, N);
        finish_kernel<<<2048, 256, 0, stream>>>(lam, seg, pooled, out, N);
    } else {
        gamma_fb<<<nb, 256, 0, stream>>>(x, seg, WpG1, gb1, WpG2, inv_counts, pooled, N);
        lambda_fb<<<nb, 256, 0, stream>>>(x, seg, WpL1, lb1, WpL2, pooled, out, N);
    }
}

// Round 4
// 647.446 us; speedup vs baseline: 1.2756x; 1.0477x over previous
//
#include <hip/hip_runtime.h>
#include <math.h>

// N=500000, F=H=128, S=256.
// out = tanh( mlp_l(x) + pooled[seg] ), pooled = lb2+gb2 + segment_mean( mlp_g_pre(x) )
// Round-4 structure: W-fragment reloads from L2 were the bottleneck (4 GB/dispatch
// of L2->L1 traffic; rounds 0-3 all latency-bound on it, cost ~ layers).
// Now: persistent blocks (256 x 512thr, 1 block/CU), packed W for both layers
// staged in LDS ONCE (64 KB), grid-stride over 128-row x tiles, double-buffered
// fp16 x tile with register prefetch (T14 split). Two passes:
//   gamma:  2-layer MLP -> in-register segmented mean -> atomics into pooled
//   lambda: 2-layer MLP -> +pooled[seg] -> tanh -> coalesced float4 stores
// Biases lb2+gb2 folded into pooled's init (prep). fp16 single-operand MFMA.

#define FW 128
#define SEGS 256
#define TILE_R 128      // rows per block-tile (8 waves x 16 rows)
#define XSTR 136        // halfs per LDS row: 272 B (16B-aligned rows)
#define BLK 512
#define NT_GRID 256     // persistent grid

typedef __attribute__((ext_vector_type(8))) _Float16 f16x8;
typedef __attribute__((ext_vector_type(4))) _Float16 f16x4;
typedef __attribute__((ext_vector_type(4))) float f32x4;

__device__ __forceinline__ float fast_tanh(float x) {
    float ax = fabsf(x);
    float t = __expf(-2.0f * ax);                // exp2-based, ~1e-6 rel err
    float r = (1.0f - t) / (1.0f + t);
    return __builtin_copysignf(r, x);
}

// --- prep: blocks 0-3 pack W fp32 -> fp16 B-fragments; block 4: inv_counts + pooled=lb2+gb2 ---
// frag f = nt*4 + ks; lane l; P[f*64+l] = 8 fp16: W[ks*32 + (l>>4)*8 + j][nt*16 + (l&15)]
__global__ void prep_kernel(const float* __restrict__ W0, const float* __restrict__ W1,
                            const float* __restrict__ W2, const float* __restrict__ W3,
                            uint4* __restrict__ P0, uint4* __restrict__ P1,
                            uint4* __restrict__ P2, uint4* __restrict__ P3,
                            const int* __restrict__ seg, float* __restrict__ inv_counts,
                            float* __restrict__ pooled,
                            const float* __restrict__ lb2, const float* __restrict__ gb2, int N)
{
    if (blockIdx.x == 4) {
        int s = threadIdx.x;
        for (int i = s; i < SEGS * FW; i += 256) {
            int c = i & (FW - 1);
            pooled[i] = lb2[c] + gb2[c];
        }
        int lo0 = 0, hi0 = N;
        while (lo0 < hi0) { int mid = (lo0 + hi0) >> 1; if (seg[mid] < s) lo0 = mid + 1; else hi0 = mid; }
        int lo1 = lo0, hi1 = N;
        while (lo1 < hi1) { int mid = (lo1 + hi1) >> 1; if (seg[mid] < s + 1) lo1 = mid + 1; else hi1 = mid; }
        int c = lo1 - lo0;
        inv_counts[s] = 1.0f / (float)(c > 0 ? c : 1);
        return;
    }
    const float* W = blockIdx.x == 0 ? W0 : blockIdx.x == 1 ? W1 : blockIdx.x == 2 ? W2 : W3;
    uint4*       P = blockIdx.x == 0 ? P0 : blockIdx.x == 1 ? P1 : blockIdx.x == 2 ? P2 : P3;
    for (int s = threadIdx.x; s < 32 * 64; s += 256) {
        int f = s >> 6, l = s & 63;
        int nt = f >> 2, ks = f & 3;
        int n = nt * 16 + (l & 15);
        int k0 = ks * 32 + ((l >> 4) << 3);
        union { _Float16 h[8]; uint4 q; } u;
        #pragma unroll
        for (int j = 0; j < 8; ++j) u.h[j] = (_Float16)W[(k0 + j) * FW + n];
        P[s] = u.q;
    }
}

// --- prefetch: issue global loads for a tile into regs (T14 issue-early phase) ---
__device__ __forceinline__ void loadX(float4 pf[8], int& sreg,
    const float* __restrict__ x, const int* __restrict__ seg, int t, int N, int tid)
{
    long r0 = (long)t * TILE_R;
    const float4* x4 = (const float4*)x;
    bool full = (r0 + TILE_R <= (long)N);
    #pragma unroll
    for (int k = 0; k < 8; ++k) {
        int j = tid + k * BLK;
        int row = j >> 5;
        pf[k] = make_float4(0.f, 0.f, 0.f, 0.f);
        if (full || r0 + row < (long)N) pf[k] = x4[r0 * 32 + j];
    }
    sreg = -1;
    if (tid < TILE_R && r0 + tid < (long)N) sreg = seg[r0 + tid];
}

// --- write-late phase: cvt fp32->fp16 and ds_write the tile ---
__device__ __forceinline__ void writeX(_Float16* Xb, int* segb,
                                       const float4 pf[8], int sreg, int tid)
{
    #pragma unroll
    for (int k = 0; k < 8; ++k) {
        int j = tid + k * BLK;
        int row = j >> 5, c4 = j & 31;
        f16x4 h;
        h.x = (_Float16)pf[k].x; h.y = (_Float16)pf[k].y;
        h.z = (_Float16)pf[k].z; h.w = (_Float16)pf[k].w;
        *(f16x4*)&Xb[row * XSTR + c4 * 4] = h;
    }
    if (tid < TILE_R) segb[tid] = sreg;
}

// --- one MFMA layer: A-frags from regs, B-frags from LDS-resident packed W ---
__device__ __forceinline__ void mfma_layer_lds(const f16x8 af[4], const uint4* Wl,
                                               int lane, f32x4 acc[8])
{
    #pragma unroll
    for (int nt = 0; nt < 8; ++nt) acc[nt] = (f32x4){0.f, 0.f, 0.f, 0.f};
    #pragma unroll
    for (int ks = 0; ks < 4; ++ks) {
        #pragma unroll
        for (int nt = 0; nt < 8; ++nt) {
            f16x8 b = __builtin_bit_cast(f16x8, Wl[(nt * 4 + ks) * 64 + lane]);
            acc[nt] = __builtin_amdgcn_mfma_f32_16x16x32_f16(af[ks], b, acc[nt], 0, 0, 0);
        }
    }
}

// --- two layers on X-buffer rows owned by this wave; h in place (wave-private rows) ---
__device__ __forceinline__ void mlp2(_Float16* Xb, const uint4* W1l, const uint4* W2l,
                                     const float b1r[8], int wv, int l15, int q,
                                     int abase, f32x4 acc[8])
{
    f16x8 xf[4];
    #pragma unroll
    for (int ks = 0; ks < 4; ++ks) xf[ks] = *(const f16x8*)&Xb[abase + ks * 32];
    mfma_layer_lds(xf, W1l, (q << 4) | l15, acc);   // lane = q*16+l15
    #pragma unroll
    for (int nt = 0; nt < 8; ++nt) {
        #pragma unroll
        for (int r = 0; r < 4; ++r)
            Xb[(wv * 16 + q * 4 + r) * XSTR + nt * 16 + l15] =
                (_Float16)fmaxf(acc[nt][r] + b1r[nt], 0.f);
    }
    // intra-wave RAW on in-place h: drain own ds_writes; pin (rule-18 pattern)
    asm volatile("s_waitcnt lgkmcnt(0)" ::: "memory");
    __builtin_amdgcn_sched_barrier(0);
    f16x8 hf[4];
    #pragma unroll
    for (int ks = 0; ks < 4; ++ks) hf[ks] = *(const f16x8*)&Xb[abase + ks * 32];
    mfma_layer_lds(hf, W2l, (q << 4) | l15, acc);
}

// --- in-register segmented mean-reduction + atomics ---
__device__ __forceinline__ void reduce_pool(const f32x4 acc[8], const int* segs,
    const float* __restrict__ inv_counts, float* __restrict__ pooled,
    int wv, int l15, int q)
{
    int rb = wv * 16;
    int sF = segs[rb], sL = segs[rb + 15];
    if (sF == sL) {
        if (sF >= 0) {
            float ic = inv_counts[sF];
            #pragma unroll
            for (int nt = 0; nt < 8; ++nt) {
                float t = (acc[nt][0] + acc[nt][1]) + (acc[nt][2] + acc[nt][3]);
                t += __shfl_xor(t, 16);
                t += __shfl_xor(t, 32);
                if (q == 0) atomicAdd(&pooled[sF * FW + nt * 16 + l15], t * ic);
            }
        }
    } else {
        int i = 0;
        while (i < 16) {
            int s = segs[rb + i];
            int e = i + 1;
            while (e < 16 && segs[rb + e] == s) ++e;
            if (s >= 0) {
                float ic = inv_counts[s];
                #pragma unroll
                for (int nt = 0; nt < 8; ++nt) {
                    float t = 0.f;
                    #pragma unroll
                    for (int r = 0; r < 4; ++r) {
                        int lr = q * 4 + r;
                        t += (lr >= i && lr < e) ? acc[nt][r] : 0.f;
                    }
                    t += __shfl_xor(t, 16);
                    t += __shfl_xor(t, 32);
                    if (q == 0) atomicAdd(&pooled[s * FW + nt * 16 + l15], t * ic);
                }
            }
            i = e;
        }
    }
}

// === pass A: persistent gamma; pooled += segment-mean contributions ===
__global__ __launch_bounds__(BLK, 2) void gamma_kernel(
    const float* __restrict__ x, const int* __restrict__ seg,
    const uint4* __restrict__ Wp1, const float* __restrict__ b1,
    const uint4* __restrict__ Wp2,
    const float* __restrict__ inv_counts, float* __restrict__ pooled,
    int N, int nTiles)
{
    __shared__ uint4    Wlds[2 * 2048];            // 64 KB: both layers' B-frags
    __shared__ _Float16 X[2][TILE_R * XSTR];       // 2 x 34 KB double-buffered x/h
    __shared__ int      segs[2][TILE_R];

    int tid = threadIdx.x;
    for (int i = tid; i < 4096; i += BLK)
        Wlds[i] = (i < 2048) ? Wp1[i] : Wp2[i - 2048];

    int wv = tid >> 6, lane = tid & 63;
    int l15 = lane & 15, q = lane >> 4;
    int abase = (wv * 16 + l15) * XSTR + q * 8;

    float b1r[8];
    #pragma unroll
    for (int nt = 0; nt < 8; ++nt) b1r[nt] = b1[nt * 16 + l15];

    float4 pf[8]; int sreg;
    loadX(pf, sreg, x, seg, blockIdx.x, N, tid);
    writeX(X[0], segs[0], pf, sreg, tid);
    __syncthreads();

    int idx = 0;
    for (int t = blockIdx.x; t < nTiles; t += gridDim.x, ++idx) {
        int cur = idx & 1, nxt = cur ^ 1;
        int tn = t + gridDim.x;
        bool hasNext = tn < nTiles;
        if (hasNext) loadX(pf, sreg, x, seg, tn, N, tid);   // overlaps compute

        f32x4 acc[8];
        mlp2(X[cur], Wlds, Wlds + 2048, b1r, wv, l15, q, abase, acc);
        reduce_pool(acc, &segs[cur][0], inv_counts, pooled, wv, l15, q);

        if (hasNext) writeX(X[nxt], segs[nxt], pf, sreg, tid);
        __syncthreads();   // stage visible before next compute; fences buffer reuse
    }
}

// === pass B: persistent lambda; out = tanh(lam + pooled[seg]), coalesced stores ===
__global__ __launch_bounds__(BLK, 2) void lambda_kernel(
    const float* __restrict__ x, const int* __restrict__ seg,
    const uint4* __restrict__ Wp1, const float* __restrict__ b1,
    const uint4* __restrict__ Wp2,
    const float* __restrict__ pooled, float* __restrict__ out,
    int N, int nTiles)
{
    __shared__ uint4    Wlds[2 * 2048];
    __shared__ _Float16 X[2][TILE_R * XSTR];
    __shared__ int      segs[2][TILE_R];

    int tid = threadIdx.x;
    for (int i = tid; i < 4096; i += BLK)
        Wlds[i] = (i < 2048) ? Wp1[i] : Wp2[i - 2048];

    int wv = tid >> 6, lane = tid & 63;
    int l15 = lane & 15, q = lane >> 4;
    int abase = (wv * 16 + l15) * XSTR + q * 8;

    float b1r[8];
    #pragma unroll
    for (int nt = 0; nt < 8; ++nt) b1r[nt] = b1[nt * 16 + l15];

    float4 pf[8]; int sreg;
    loadX(pf, sreg, x, seg, blockIdx.x, N, tid);
    writeX(X[0], segs[0], pf, sreg, tid);
    __syncthreads();

    int idx = 0;
    for (int t = blockIdx.x; t < nTiles; t += gridDim.x, ++idx) {
        int cur = idx & 1, nxt = cur ^ 1;
        int tn = t + gridDim.x;
        bool hasNext = tn < nTiles;
        if (hasNext) loadX(pf, sreg, x, seg, tn, N, tid);   // overlaps compute

        f32x4 acc[8];
        mlp2(X[cur], Wlds, Wlds + 2048, b1r, wv, l15, q, abase, acc);

        // lam (pre-bias2) -> fp16 into own rows of X[cur] (h dead)
        #pragma unroll
        for (int nt = 0; nt < 8; ++nt) {
            #pragma unroll
            for (int r = 0; r < 4; ++r)
                X[cur][(wv * 16 + q * 4 + r) * XSTR + nt * 16 + l15] = (_Float16)acc[nt][r];
        }
        __syncthreads();   // lam visible block-wide (implies lgkm drain)

        // coalesced epilogue: 512 thr = 128 rows x 4 chunks of 32 cols
        {
            int orow = tid >> 2, ch = tid & 3;
            long grow = (long)t * TILE_R + orow;
            if (grow < (long)N) {
                int s = segs[cur][orow];
                const _Float16* lsrc = &X[cur][orow * XSTR + ch * 32];
                const float4* prow = (const float4*)&pooled[s * FW + ch * 32];
                float4* dst = (float4*)(out + grow * FW + ch * 32);
                #pragma unroll
                for (int u = 0; u < 4; ++u) {
                    f16x8 lv = *(const f16x8*)&lsrc[u * 8];
                    float4 p0 = prow[2 * u], p1 = prow[2 * u + 1];
                    float4 o0, o1;
                    o0.x = fast_tanh((float)lv[0] + p0.x);
                    o0.y = fast_tanh((float)lv[1] + p0.y);
                    o0.z = fast_tanh((float)lv[2] + p0.z);
                    o0.w = fast_tanh((float)lv[3] + p0.w);
                    o1.x = fast_tanh((float)lv[4] + p1.x);
                    o1.y = fast_tanh((float)lv[5] + p1.y);
                    o1.z = fast_tanh((float)lv[6] + p1.z);
                    o1.w = fast_tanh((float)lv[7] + p1.w);
                    dst[2 * u] = o0; dst[2 * u + 1] = o1;
                }
            }
        }

        if (hasNext) writeX(X[nxt], segs[nxt], pf, sreg, tid);
        __syncthreads();
    }
}

extern "C" void kernel_launch(void* const* d_in, const int* in_sizes, int n_in,
                              void* d_out, int out_size, void* d_ws, size_t ws_size,
                              hipStream_t stream) {
    const float* x   = (const float*)d_in[0];
    const int*   seg = (const int*)  d_in[1];
    const float* lW1 = (const float*)d_in[2];
    const float* lb1 = (const float*)d_in[3];
    const float* lW2 = (const float*)d_in[4];
    const float* lb2 = (const float*)d_in[5];
    const float* gW1 = (const float*)d_in[6];
    const float* gb1 = (const float*)d_in[7];
    const float* gW2 = (const float*)d_in[8];
    const float* gb2 = (const float*)d_in[9];
    float* out = (float*)d_out;

    const int N = in_sizes[0] / FW;            // 500000

    char* ws = (char*)d_ws;
    float* pooled     = (float*)ws;                         // 256*128*4 = 131072 B
    float* inv_counts = (float*)(ws + 131072);              // 1024 B
    uint4* WpL1 = (uint4*)(ws + 132096);                    // 32 KB each
    uint4* WpL2 = WpL1 + 2048;
    uint4* WpG1 = WpL2 + 2048;
    uint4* WpG2 = WpG1 + 2048;

    prep_kernel<<<5, 256, 0, stream>>>(lW1, lW2, gW1, gW2, WpL1, WpL2, WpG1, WpG2,
                                       seg, inv_counts, pooled, lb2, gb2, N);

    int nTiles = (N + TILE_R - 1) / TILE_R;    // 3907
    gamma_kernel<<<NT_GRID, BLK, 0, stream>>>(x, seg, WpG1, gb1, WpG2,
                                              inv_counts, pooled, N, nTiles);
    lambda_kernel<<<NT_GRID, BLK, 0, stream>>>(x, seg, WpL1, lb1, WpL2,
                                               pooled, out, N, nTiles);
}